// Round 2
// baseline (2605.769 us; speedup 1.0000x reference)
//
#include <hip/hip_runtime.h>
#include <hip/hip_bf16.h>

// Problem constants: N=10000, D_IN=128, F1=F2=20, D_OUT=128
constexpr int NN   = 10000;
constexpr int DIN  = 128;
constexpr int F    = 20;
constexpr int DOUT = 128;

// adjmm tiling: 1024 rows/block (4 per thread), k split 50 ways (200 k/block)
constexpr int TM     = 1024;
constexpr int RPT    = 4;
constexpr int KSPLIT = 50;
constexpr int KRANGE = NN / KSPLIT;            // 200
constexpr int ROWBLK = (NN + TM - 1) / TM;     // 10

// ---------------------------------------------------------------------------
// t1[i,f] = sum_k x[i,k] * W[k,f]   (K=128, F=20)
// ---------------------------------------------------------------------------
__global__ __launch_bounds__(256) void gemm_x_w1(const float* __restrict__ x,
                                                 const float* __restrict__ W,
                                                 float* __restrict__ out) {
    int t = blockIdx.x * 256 + threadIdx.x;
    if (t >= NN * F) return;
    int i = t / F, f = t % F;
    const float4* xp = (const float4*)(x + (size_t)i * DIN);
    float s = 0.f;
#pragma unroll
    for (int k4 = 0; k4 < DIN / 4; ++k4) {
        float4 xv = xp[k4];
        int k = k4 * 4;
        s += xv.x * W[(k + 0) * F + f];
        s += xv.y * W[(k + 1) * F + f];
        s += xv.z * W[(k + 2) * F + f];
        s += xv.w * W[(k + 3) * F + f];
    }
    out[t] = s;
}

// ---------------------------------------------------------------------------
// out[i,g] = sum_f relu(in[i,f] + b[f]) * W[f,g]   (fused bias+relu+gemm, 20x20)
// ---------------------------------------------------------------------------
__global__ __launch_bounds__(256) void fused_relu_gemm(const float* __restrict__ in,
                                                       const float* __restrict__ b,
                                                       const float* __restrict__ W,
                                                       float* __restrict__ out) {
    int t = blockIdx.x * 256 + threadIdx.x;
    if (t >= NN * F) return;
    int i = t / F, g = t % F;
    const float* hp = in + (size_t)i * F;
    float s = 0.f;
#pragma unroll
    for (int f = 0; f < F; ++f) s += fmaxf(hp[f] + b[f], 0.f) * W[f * F + g];
    out[t] = s;
}

// ---------------------------------------------------------------------------
// out[t] = relu(in[t] + b[t % F])
// ---------------------------------------------------------------------------
__global__ __launch_bounds__(256) void bias_relu(const float* __restrict__ in,
                                                 const float* __restrict__ b,
                                                 float* __restrict__ out) {
    int t = blockIdx.x * 256 + threadIdx.x;
    if (t >= NN * F) return;
    out[t] = fmaxf(in[t] + b[t % F], 0.f);
}

// ---------------------------------------------------------------------------
// adjmm: out[i,:F] += adj[i, kr] @ t[kr, :F] for this block's 200-wide k-range.
// t chunk lives in LDS (16 KB), read via wave-uniform ds_read_b128 (broadcast).
// adj streamed straight to registers: 16 k's per iter = one 64B line per row.
// 4 rows per thread amortize each t read 4x.
// ---------------------------------------------------------------------------
__global__ __launch_bounds__(256) void adjmm(const float* __restrict__ adj,
                                             const float* __restrict__ t,
                                             float* __restrict__ out) {
    __shared__ float ts[KRANGE * F];   // 200*20*4 = 16000 B

    const int tid = threadIdx.x;
    const int row0 = blockIdx.x * TM;
    const int k0 = blockIdx.y * KRANGE;

    // stage t[k0..k0+200) x 20 -> LDS, coalesced float4
    {
        const float4* src = (const float4*)(t + (size_t)k0 * F);
        float4* dst = (float4*)ts;
#pragma unroll
        for (int i = 0; i < KRANGE * F / 4 / 256 + 1; ++i) {
            int idx = tid + i * 256;
            if (idx < KRANGE * F / 4) dst[idx] = src[idx];
        }
    }
    __syncthreads();

    int rows[RPT];
    const float* ap[RPT];
#pragma unroll
    for (int r = 0; r < RPT; ++r) {
        rows[r] = row0 + tid + 256 * r;
        int cr = rows[r] < NN ? rows[r] : NN - 1;
        ap[r] = adj + (size_t)cr * NN + k0;
    }

    float4 acc[RPT][5];
#pragma unroll
    for (int r = 0; r < RPT; ++r)
#pragma unroll
        for (int c = 0; c < 5; ++c) acc[r][c] = make_float4(0.f, 0.f, 0.f, 0.f);

    // main: 12 iters x 16 k  (192), tail below
    for (int it = 0; it < KRANGE / 16; ++it) {
        float4 a[RPT][4];
#pragma unroll
        for (int r = 0; r < RPT; ++r)
#pragma unroll
            for (int q = 0; q < 4; ++q)
                a[r][q] = *(const float4*)(ap[r] + it * 16 + q * 4);
#pragma unroll
        for (int q = 0; q < 4; ++q) {
#pragma unroll
            for (int j = 0; j < 4; ++j) {
                const int k = it * 16 + q * 4 + j;
                const float4* tv = (const float4*)(ts + k * F);
                float av[RPT];
#pragma unroll
                for (int r = 0; r < RPT; ++r) av[r] = ((const float*)&a[r][q])[j];
#pragma unroll
                for (int c = 0; c < 5; ++c) {
                    float4 tc = tv[c];
#pragma unroll
                    for (int r = 0; r < RPT; ++r) {
                        acc[r][c].x += av[r] * tc.x;
                        acc[r][c].y += av[r] * tc.y;
                        acc[r][c].z += av[r] * tc.z;
                        acc[r][c].w += av[r] * tc.w;
                    }
                }
            }
        }
    }
    // tail: k = 192..199, 2 iters of 4
    for (int kt = (KRANGE / 16) * 16; kt < KRANGE; kt += 4) {
        float4 a[RPT];
#pragma unroll
        for (int r = 0; r < RPT; ++r) a[r] = *(const float4*)(ap[r] + kt);
#pragma unroll
        for (int j = 0; j < 4; ++j) {
            const int k = kt + j;
            const float4* tv = (const float4*)(ts + k * F);
            float av[RPT];
#pragma unroll
            for (int r = 0; r < RPT; ++r) av[r] = ((const float*)&a[r])[j];
#pragma unroll
            for (int c = 0; c < 5; ++c) {
                float4 tc = tv[c];
#pragma unroll
                for (int r = 0; r < RPT; ++r) {
                    acc[r][c].x += av[r] * tc.x;
                    acc[r][c].y += av[r] * tc.y;
                    acc[r][c].z += av[r] * tc.z;
                    acc[r][c].w += av[r] * tc.w;
                }
            }
        }
    }

#pragma unroll
    for (int r = 0; r < RPT; ++r) {
        if (rows[r] < NN) {
            float* op = out + (size_t)rows[r] * F;
#pragma unroll
            for (int c = 0; c < 5; ++c) {
                atomicAdd(op + c * 4 + 0, acc[r][c].x);
                atomicAdd(op + c * 4 + 1, acc[r][c].y);
                atomicAdd(op + c * 4 + 2, acc[r][c].z);
                atomicAdd(op + c * 4 + 3, acc[r][c].w);
            }
        }
    }
}

// ---------------------------------------------------------------------------
// out[i,f] = relu( relu( sum_g u[i,g]*W3[g,f] + b3[f] ) + x[i,f] )
// ---------------------------------------------------------------------------
__global__ __launch_bounds__(256) void final_fuse(const float* __restrict__ u,
                                                  const float* __restrict__ W3,
                                                  const float* __restrict__ b3,
                                                  const float* __restrict__ x,
                                                  float* __restrict__ out) {
    int t = blockIdx.x * 256 + threadIdx.x;
    if (t >= NN * DOUT) return;
    int i = t / DOUT, f = t % DOUT;
    const float* up = u + (size_t)i * F;
    float s = b3[f];
#pragma unroll
    for (int g = 0; g < F; ++g) s += up[g] * W3[g * DOUT + f];
    float h = fmaxf(s, 0.f);
    out[t] = fmaxf(h + x[t], 0.f);
}

// ---------------------------------------------------------------------------
extern "C" void kernel_launch(void* const* d_in, const int* in_sizes, int n_in,
                              void* d_out, int out_size, void* d_ws, size_t ws_size,
                              hipStream_t stream) {
    const float* x   = (const float*)d_in[0];
    const float* adj = (const float*)d_in[1];
    const float* W1  = (const float*)d_in[2];
    const float* b1  = (const float*)d_in[3];
    const float* W2  = (const float*)d_in[4];
    const float* b2  = (const float*)d_in[5];
    const float* W3  = (const float*)d_in[6];
    const float* b3  = (const float*)d_in[7];
    float* out = (float*)d_out;

    float* A = (float*)d_ws;            // N x F
    float* B = A + NN * F;              // N x F
    float* C = B + NN * F;              // N x F
    const size_t nf_bytes = (size_t)NN * F * sizeof(float);

    const int blk_nf = (NN * F + 255) / 256;        // 782
    const int blk_no = (NN * DOUT + 255) / 256;     // 5000
    dim3 adj_grid(ROWBLK, KSPLIT);                  // 10 x 50 = 500 blocks

    // Layer 1: t1 = x@W1 ; B = adj@t1
    gemm_x_w1<<<blk_nf, 256, 0, stream>>>(x, W1, A);
    hipMemsetAsync(B, 0, nf_bytes, stream);
    adjmm<<<adj_grid, 256, 0, stream>>>(adj, A, B);

    // Layer 2: t2 = relu(B+b1)@W2 ; B2 = adj@t2
    fused_relu_gemm<<<blk_nf, 256, 0, stream>>>(B, b1, W2, A);
    hipMemsetAsync(C, 0, nf_bytes, stream);
    adjmm<<<adj_grid, 256, 0, stream>>>(adj, A, C);

    // Layer 3 (reassociated): h2 = relu(C+b2) ; u = adj@h2 ; out = relu(relu(u@W3+b3)+x)
    bias_relu<<<blk_nf, 256, 0, stream>>>(C, b2, B);
    hipMemsetAsync(A, 0, nf_bytes, stream);
    adjmm<<<adj_grid, 256, 0, stream>>>(adj, B, A);
    final_fuse<<<blk_no, 256, 0, stream>>>(A, W3, b3, x, out);
}